// Round 7
// baseline (350.067 us; speedup 1.0000x reference)
//
#include <hip/hip_runtime.h>
#include <hip/hip_bf16.h>
#include <math.h>

// ---------------------------------------------------------------------------
// FlaxLTX2AudioAttnBlock: GN -> QKV proj -> softmax(QK^T/sqrt(C)) V -> proj -> +x
// B=4, N=4096 tokens/batch, C=512, G=32 groups.
// R7: LDS-staged vectorized epilogue for ALL gemm256 variants (bf16x8/float4
//     coalesced stores instead of 128 scalar stores/thread; row-sums computed
//     during read-back). Main loop / schedule unchanged from R5/R6.
// ---------------------------------------------------------------------------

typedef __bf16 bf16;
typedef float f32x4 __attribute__((ext_vector_type(4)));
typedef __bf16 bf16x8 __attribute__((ext_vector_type(8)));
typedef __bf16 bf16x4 __attribute__((ext_vector_type(4)));

#define AS1 __attribute__((address_space(1)))
#define AS3 __attribute__((address_space(3)))

#define NB   4
#define NTOK 4096
#define CCH  512
#define NGRP 32

__device__ __forceinline__ void gload_lds16(const void* g, void* l) {
  __builtin_amdgcn_global_load_lds((AS1 void*)(g), (AS3 void*)(l), 16, 0, 0);
}

// ---------------- GroupNorm stage 1: partial sums ---------------------------
__global__ __launch_bounds__(256) void gn_partial(const float4* __restrict__ x4,
                                                  float* __restrict__ partials) {
  const int chunk = blockIdx.x, b = blockIdx.y;
  const int tid = threadIdx.x;
  const size_t base = ((size_t)b * NTOK + (size_t)chunk * 64) * 128;  // float4s
  float s = 0.f, ss = 0.f;
  #pragma unroll 4
  for (int it = 0; it < 32; ++it) {
    const float4 v = x4[base + it * 256 + tid];
    s  += v.x + v.y + v.z + v.w;
    ss += v.x * v.x + v.y * v.y + v.z * v.z + v.w * v.w;
  }
  __shared__ float ls[256], lss[256];
  ls[tid] = s; lss[tid] = ss;
  __syncthreads();
  if (tid < 32) {
    float ps = 0.f, pss = 0.f;
    #pragma unroll
    for (int j = 0; j < 4; ++j) {
      ps  += ls[tid * 4 + j] + ls[128 + tid * 4 + j];
      pss += lss[tid * 4 + j] + lss[128 + tid * 4 + j];
    }
    const size_t o = (((size_t)b * 64 + chunk) * 32 + tid) * 2;
    partials[o] = ps; partials[o + 1] = pss;
  }
}

// ---------------- GroupNorm stage 2: reduce 64 chunks -> stats --------------
__global__ __launch_bounds__(128) void gn_reduce(const float* __restrict__ partials,
                                                 float* __restrict__ stats) {
  const int tid = threadIdx.x;          // tid = b*32 + g
  const int b = tid >> 5, g = tid & 31;
  float s = 0.f, ss = 0.f;
  for (int c = 0; c < 64; ++c) {
    const size_t o = (((size_t)b * 64 + c) * 32 + g) * 2;
    s += partials[o]; ss += partials[o + 1];
  }
  const float inv = 1.f / (NTOK * 16.f);
  const float mean = s * inv;
  const float var = ss * inv - mean * mean;
  stats[tid * 2] = mean;
  stats[tid * 2 + 1] = rsqrtf(var + 1e-6f);
}

// ---------------- normalize + affine + cast to bf16 -------------------------
__global__ __launch_bounds__(256) void gn_apply(const float4* __restrict__ x4,
                                                const float* __restrict__ stats,
                                                const float* __restrict__ gsc,
                                                const float* __restrict__ gbi,
                                                bf16* __restrict__ hf) {
  const int i = blockIdx.x * 256 + threadIdx.x;   // over 2,097,152 float4s
  const float4 v = x4[i];
  const size_t e = (size_t)i * 4;
  const int c = (int)(e & (CCH - 1));
  const int b = (int)(e >> 21);
  const int g = c >> 4;
  const float mean = stats[(b * NGRP + g) * 2];
  const float rstd = stats[(b * NGRP + g) * 2 + 1];
  bf16x4 o;
  o[0] = (bf16)((v.x - mean) * rstd * gsc[c + 0] + gbi[c + 0]);
  o[1] = (bf16)((v.y - mean) * rstd * gsc[c + 1] + gbi[c + 1]);
  o[2] = (bf16)((v.z - mean) * rstd * gsc[c + 2] + gbi[c + 2]);
  o[3] = (bf16)((v.w - mean) * rstd * gsc[c + 3] + gbi[c + 3]);
  *reinterpret_cast<bf16x4*>(&hf[e]) = o;
}

// ---------------- weight transpose+cast (wq, wk) + bias concat --------------
__global__ __launch_bounds__(256) void wcast_t(const float* __restrict__ wq,
                                               const float* __restrict__ wk,
                                               const float* __restrict__ bq,
                                               const float* __restrict__ bk,
                                               bf16* __restrict__ dst,
                                               float* __restrict__ bcat) {
  const int w = blockIdx.y;                // 0 = wq, 1 = wk
  const float* src = (w == 0) ? wq : wk;
  bf16* out = dst + (size_t)w * CCH * CCH;
  const int t = blockIdx.x;                // 8x8 tiles of 64x64
  const int tr = t >> 3, tc = t & 7;
  if (t == 0) {
    const float* bsrc = (w == 0) ? bq : bk;
    for (int i = threadIdx.x; i < CCH; i += 256) bcat[w * CCH + i] = bsrc[i];
  }
  __shared__ float tile[64][65];
  for (int i = threadIdx.x; i < 4096; i += 256) {
    const int r = i >> 6, c = i & 63;
    tile[r][c] = src[(size_t)(tr * 64 + r) * CCH + tc * 64 + c];
  }
  __syncthreads();
  for (int i = threadIdx.x; i < 4096; i += 256) {
    const int r = i >> 6, c = i & 63;
    out[(size_t)(tc * 64 + r) * CCH + tr * 64 + c] = (bf16)tile[c][r];
  }
}

// ---------------- prep: W'^T = (wv@wo)^T bf16; block 0 also bpv -------------
__global__ __launch_bounds__(256) void prep_w(const float* __restrict__ wv,
                                              const float* __restrict__ wo,
                                              const float* __restrict__ bv,
                                              const float* __restrict__ bo,
                                              bf16* __restrict__ wpT,
                                              float* __restrict__ bpv) {
  const int ta = blockIdx.x >> 3, tb = blockIdx.x & 7;   // 8x8 blocks of 64x64
  __shared__ float woS[64][65];   // [kk][aa]
  __shared__ float wvS[64][65];   // [bb][kk]
  const int t = threadIdx.x;
  if (blockIdx.x == 0) {           // bpv = bv @ wo + bo
    for (int j = t; j < CCH; j += 256) {
      float a2 = bo[j];
      for (int k2 = 0; k2 < CCH; ++k2) a2 += bv[k2] * wo[(size_t)k2 * CCH + j];
      bpv[j] = a2;
    }
  }
  const int aa0 = (t & 15) * 4, bb0 = (t >> 4) * 4;
  float acc[4][4] = {};
  for (int kt = 0; kt < CCH; kt += 64) {
    for (int i = t; i < 4096; i += 256) {
      const int r = i >> 6, c = i & 63;
      woS[r][c] = wo[(size_t)(kt + r) * CCH + ta * 64 + c];
      wvS[r][c] = wv[(size_t)(tb * 64 + r) * CCH + kt + c];
    }
    __syncthreads();
    #pragma unroll 8
    for (int kk = 0; kk < 64; ++kk) {
      float wo4[4], wv4[4];
      #pragma unroll
      for (int i2 = 0; i2 < 4; ++i2) { wo4[i2] = woS[kk][aa0 + i2]; wv4[i2] = wvS[bb0 + i2][kk]; }
      #pragma unroll
      for (int a2 = 0; a2 < 4; ++a2)
        #pragma unroll
        for (int b2 = 0; b2 < 4; ++b2)
          acc[a2][b2] += wo4[a2] * wv4[b2];
    }
    __syncthreads();
  }
  #pragma unroll
  for (int a2 = 0; a2 < 4; ++a2)
    #pragma unroll
    for (int b2 = 0; b2 < 4; ++b2)
      wpT[(size_t)(ta * 64 + aa0 + a2) * CCH + tb * 64 + bb0 + b2] = (bf16)acc[a2][b2];
}

// ---------------- row-sum reduce: partials[rows][16] -> rinv = 1/sum --------
__global__ __launch_bounds__(256) void rowsum_inv(const float* __restrict__ partials,
                                                  float* __restrict__ rinv) {
  const int row = blockIdx.x * 256 + threadIdx.x;
  const float* p = partials + (size_t)row * 16;
  float s = 0.f;
  #pragma unroll
  for (int j = 0; j < 16; ++j) s += p[j];
  rinv[row] = 1.f / s;
}

// ---------------- 4-phase 256xBN MFMA GEMM: C = A @ Bt^T (+ epilogue) -------
// 512 threads = 8 waves (2M x 4N). BM=256, BNt in {256,128}, BK=64.
// Main loop as R5 (4-phase merged, B-frags register-resident, counted vmcnt).
// Epilogue: LDS-staged per wm-half -> vectorized coalesced stores (bf16x8 or
// float4); scores row-sums computed during read-back (2 shfl per row-slice).
// EPI: 0 = (+bias)*scale on cols<CCH, bf16 out (QK proj)
//      1 = exp(min(val,40)) bf16 out + per-block row-sum partials (scores)
//      2 = *rinv[row] +bias +resid, f32 out (PV -> final output)
//      3 = plain bf16 out (V'^T)
template <int BNt, int EPI>
__global__ __launch_bounds__(512, 2) void gemm256(
    const bf16* __restrict__ A, int lda, size_t sA,
    const bf16* __restrict__ Bt, int ldb, size_t sB,
    void* __restrict__ C, int ldc, size_t sC,
    const float* __restrict__ bias, const float* __restrict__ resid,
    float* __restrict__ partials, const float* __restrict__ rinv,
    int M, int N, int K, float scale) {
  constexpr int BK = 64;
  constexpr int WN = BNt / 4;        // per-wave N extent (64 or 32)
  constexpr int NREP = WN / 16;      // N fragments per wave (4 or 2)
  constexpr int BH = BNt / 2;        // B half-tile rows (128 or 64)
  constexpr int BISS = BNt / 128;    // gload issues per B half (2 or 1)
  constexpr int PADF = 4;
  constexpr int LDE = BNt + PADF;    // epilogue LDS row stride (f32)
  constexpr int STAGE_BYTES = 2 * (256 + BNt) * BK * 2;
  constexpr int EPIB = 128 * LDE * 4;
  constexpr int SMEM_BYTES = STAGE_BYTES > EPIB ? STAGE_BYTES : EPIB;

  __shared__ __align__(16) char smem[SMEM_BYTES];
  typedef bf16 AlT[256 * BK];
  typedef bf16 BlT[BNt * BK];
  AlT* Al = (AlT*)smem;
  BlT* Bl = (BlT*)(smem + 2 * 256 * BK * 2);

  A += (size_t)blockIdx.y * sA;
  Bt += (size_t)blockIdx.y * sB;

  const int tid = threadIdx.x;
  const int lane = tid & 63;
  const int wave = tid >> 6;
  const int wm = wave >> 2, wn = wave & 3;
  const int fr = lane & 15, fq = lane >> 4;
  const int nbn = N / BNt;
  int bx = blockIdx.x;
  const int nwg = gridDim.x;
  bx = (bx & 7) * (nwg >> 3) + (bx >> 3);    // XCD swizzle (all grids %8==0)
  const int bm = bx / nbn, bn = bx % nbn;

  // staging: thread covers 16B chunk; T2: global chunk = lds chunk ^ (row&7)
  const int srow = tid >> 3;                              // 0..63
  const int scol = (((tid & 7) ^ (srow & 7)) * 8);
  const bf16* Ab = A + (size_t)(bm * 256 + srow) * lda + scol;
  const bf16* Bb = Bt + (size_t)(bn * BNt + srow) * ldb + scol;

  // swizzled ds_read chunk offsets (elems): chunk (ks*4+fq) ^ (fr&7)
  const int xk = fr & 7;
  const int c0 = ((0 + fq) ^ xk) * 8;
  const int c1 = ((4 + fq) ^ xk) * 8;
  const int aroff = (wm * 128 + fr) * BK;
  const int broff = (wn * WN + fr) * BK;

  f32x4 acc[8][NREP];
  #pragma unroll
  for (int m2 = 0; m2 < 8; ++m2)
    #pragma unroll
    for (int n2 = 0; n2 < NREP; ++n2)
      acc[m2][n2] = f32x4{0.f, 0.f, 0.f, 0.f};
  bf16x8 af[4][2];
  bf16x8 bfr[NREP][2];

#define STAGE_A(buf, h, kt)                                                     \
  { gload_lds16(Ab + (size_t)((h) * 128) * lda + (kt),                          \
                &Al[buf][(h) * 8192 + wave * 512]);                             \
    gload_lds16(Ab + (size_t)((h) * 128 + 64) * lda + (kt),                     \
                &Al[buf][(h) * 8192 + 4096 + wave * 512]); }
#define STAGE_B(buf, h, kt)                                                     \
  { gload_lds16(Bb + (size_t)((h) * BH) * ldb + (kt),                           \
                &Bl[buf][(h) * BH * BK + wave * 512]);                          \
    if (BISS == 2)                                                              \
      gload_lds16(Bb + (size_t)((h) * BH + 64) * ldb + (kt),                    \
                  &Bl[buf][(h) * BH * BK + 4096 + wave * 512]); }
#define LOADA(buf, mh)                                                          \
  { _Pragma("unroll") for (int mi = 0; mi < 4; ++mi) {                          \
      af[mi][0] = *(const bf16x8*)&Al[buf][aroff + ((mh) * 64 + mi * 16) * BK + c0]; \
      af[mi][1] = *(const bf16x8*)&Al[buf][aroff + ((mh) * 64 + mi * 16) * BK + c1]; } }
#define LOADB(buf)                                                              \
  { _Pragma("unroll") for (int ni = 0; ni < NREP; ++ni) {                       \
      bfr[ni][0] = *(const bf16x8*)&Bl[buf][broff + (ni * 16) * BK + c0];       \
      bfr[ni][1] = *(const bf16x8*)&Bl[buf][broff + (ni * 16) * BK + c1]; } }
#define MMA(mh)                                                                 \
  { __builtin_amdgcn_s_setprio(1);                                              \
    _Pragma("unroll") for (int mi = 0; mi < 4; ++mi)                            \
      _Pragma("unroll") for (int ni = 0; ni < NREP; ++ni) {                     \
        acc[(mh) * 4 + mi][ni] = __builtin_amdgcn_mfma_f32_16x16x32_bf16(       \
            af[mi][0], bfr[ni][0], acc[(mh) * 4 + mi][ni], 0, 0, 0);            \
        acc[(mh) * 4 + mi][ni] = __builtin_amdgcn_mfma_f32_16x16x32_bf16(       \
            af[mi][1], bfr[ni][1], acc[(mh) * 4 + mi][ni], 0, 0, 0); }          \
    __builtin_amdgcn_s_setprio(0); }
#define BARX() __builtin_amdgcn_s_barrier()
#define PIN() __builtin_amdgcn_sched_barrier(0)
#define LGKM0() { asm volatile("s_waitcnt lgkmcnt(0)" ::: "memory"); PIN(); }
#define VMW(n) asm volatile("s_waitcnt vmcnt(" #n ")" ::: "memory")
#define VMWSS() { if (BISS == 2) VMW(4); else VMW(3); }   // steady-state count

  // prologue: tile0 (4 halves) + A0,B0 of tile1 -> keep 2 halves in flight
  STAGE_A(0, 0, 0); STAGE_A(0, 1, 0);
  STAGE_B(0, 0, 0); STAGE_B(0, 1, 0);
  STAGE_A(1, 0, BK); STAGE_B(1, 0, BK);
  VMWSS();
  BARX();

  const int niter = K >> 7;      // 2 K-tiles (BK=64) per iteration
  for (int j = 0; j < niter; ++j) {
    const int kt1 = j * 128 + 64;
    const int kt2 = kt1 + 64, kt3 = kt1 + 128;
    const bool last = (j == niter - 1);
    // P1: tile t (buf0) mh=0 + B-all; stage A1(t+1),B1(t+1)->buf1
    LOADA(0, 0); LOADB(0); STAGE_A(1, 1, kt1); STAGE_B(1, 1, kt1);
    PIN(); BARX(); LGKM0(); MMA(0); BARX();
    // P2: mh=1 (B resident); stage A0(t+2),B0(t+2)->buf0; counted vmcnt
    LOADA(0, 1); if (!last) { STAGE_A(0, 0, kt2); STAGE_B(0, 0, kt2); }
    PIN(); BARX(); LGKM0(); MMA(1);
    if (last) { VMW(0); } else VMWSS();
    BARX();
    // P3: tile t+1 (buf1) mh=0 + B-all; stage A1(t+2),B1(t+2)->buf0
    LOADA(1, 0); LOADB(1); if (!last) { STAGE_A(0, 1, kt2); STAGE_B(0, 1, kt2); }
    PIN(); BARX(); LGKM0(); MMA(0); BARX();
    // P4: mh=1; stage A0(t+3),B0(t+3)->buf1; counted vmcnt
    LOADA(1, 1); if (!last) { STAGE_A(1, 0, kt3); STAGE_B(1, 0, kt3); }
    PIN(); BARX(); LGKM0(); MMA(1);
    if (!last) VMWSS();
    BARX();
  }

  // ---- LDS-staged vectorized epilogue ----
  {
    constexpr int CH = BNt / 4;              // cols per read-back thread
    float* E = (float*)smem;                 // [128][LDE] f32, reuses staging
    const int er = tid >> 2;                 // read-back row 0..127
    const int ec = tid & 3;                  // read-back col chunk
    const int ccolb = bn * BNt + ec * CH;
    const float ascale = (EPI == 0 && (bn * BNt) < CCH) ? scale : 1.f;
    #pragma unroll
    for (int h = 0; h < 2; ++h) {
      __syncthreads();
      if (wm == h) {
        #pragma unroll
        for (int mh = 0; mh < 2; ++mh)
          #pragma unroll
          for (int mi = 0; mi < 4; ++mi)
            #pragma unroll
            for (int nr = 0; nr < NREP; ++nr)
              #pragma unroll
              for (int jj = 0; jj < 4; ++jj) {
                float v = acc[mh * 4 + mi][nr][jj];
                if constexpr (EPI == 1) v = __expf(fminf(v, 40.f));
                E[(mh * 64 + mi * 16 + fq * 4 + jj) * LDE + wn * WN + nr * 16 + fr] = v;
              }
      }
      __syncthreads();
      const int grow = bm * 256 + h * 128 + er;
      if constexpr (EPI == 2) {
        const float ri = rinv[(size_t)blockIdx.y * M + grow];
        float* Cf = (float*)C + (size_t)blockIdx.y * sC + (size_t)grow * ldc + ccolb;
        const float* Rz = resid + (size_t)blockIdx.y * sC + (size_t)grow * ldc + ccolb;
        #pragma unroll
        for (int i = 0; i < CH / 4; ++i) {
          const f32x4 v4 = *(const f32x4*)&E[er * LDE + ec * CH + i * 4];
          const float4 b4 = *(const float4*)&bias[ccolb + i * 4];
          const float4 r4 = *(const float4*)&Rz[i * 4];
          float4 o4;
          o4.x = v4[0] * ri + b4.x + r4.x;
          o4.y = v4[1] * ri + b4.y + r4.y;
          o4.z = v4[2] * ri + b4.z + r4.z;
          o4.w = v4[3] * ri + b4.w + r4.w;
          *(float4*)&Cf[i * 4] = o4;
        }
      } else {
        bf16* Cb = (bf16*)C + (size_t)blockIdx.y * sC + (size_t)grow * ldc + ccolb;
        float rs = 0.f;
        #pragma unroll
        for (int i = 0; i < CH / 8; ++i) {
          f32x4 a4 = *(const f32x4*)&E[er * LDE + ec * CH + i * 8];
          f32x4 b4 = *(const f32x4*)&E[er * LDE + ec * CH + i * 8 + 4];
          if constexpr (EPI == 0) {
            const float4 ba = *(const float4*)&bias[ccolb + i * 8];
            const float4 bb = *(const float4*)&bias[ccolb + i * 8 + 4];
            a4[0] = (a4[0] + ba.x) * ascale; a4[1] = (a4[1] + ba.y) * ascale;
            a4[2] = (a4[2] + ba.z) * ascale; a4[3] = (a4[3] + ba.w) * ascale;
            b4[0] = (b4[0] + bb.x) * ascale; b4[1] = (b4[1] + bb.y) * ascale;
            b4[2] = (b4[2] + bb.z) * ascale; b4[3] = (b4[3] + bb.w) * ascale;
          }
          if constexpr (EPI == 1)
            rs += a4[0] + a4[1] + a4[2] + a4[3] + b4[0] + b4[1] + b4[2] + b4[3];
          bf16x8 o;
          #pragma unroll
          for (int jb = 0; jb < 4; ++jb) { o[jb] = (bf16)a4[jb]; o[4 + jb] = (bf16)b4[jb]; }
          *(bf16x8*)&Cb[i * 8] = o;
        }
        if constexpr (EPI == 1) {
          rs += __shfl_xor(rs, 1);
          rs += __shfl_xor(rs, 2);
          if (ec == 0)
            partials[((size_t)blockIdx.y * M + grow) * (size_t)nbn + bn] = rs;
        }
      }
    }
  }
#undef STAGE_A
#undef STAGE_B
#undef LOADA
#undef LOADB
#undef MMA
#undef BARX
#undef PIN
#undef LGKM0
#undef VMW
#undef VMWSS
}

// ---------------------------------------------------------------------------
extern "C" void kernel_launch(void* const* d_in, const int* in_sizes, int n_in,
                              void* d_out, int out_size, void* d_ws, size_t ws_size,
                              hipStream_t stream) {
  const float* x   = (const float*)d_in[0];
  const float* gsc = (const float*)d_in[1];
  const float* gbi = (const float*)d_in[2];
  const float* wq  = (const float*)d_in[3];
  const float* bq  = (const float*)d_in[4];
  const float* wk  = (const float*)d_in[5];
  const float* bk  = (const float*)d_in[6];
  const float* wv  = (const float*)d_in[7];
  const float* bv  = (const float*)d_in[8];
  const float* wo  = (const float*)d_in[9];
  const float* bo  = (const float*)d_in[10];
  float* out = (float*)d_out;
  char* ws = (char*)d_ws;

  const float sscale = 0.044194173824159216f;  // 1/sqrt(512)
  const bool batched = ws_size >= 187311104ULL;

  if (batched) {
    // S_all[134.2M] | qk[33.6M] | vt[16.8M] | wT | bcat/bpv/stats | parts |
    // spart[1M] | rinv
    bf16*  S_all = (bf16*)(ws + 0);
    bf16*  hf    = (bf16*)(ws + 0);             // alias: dead before S written
    bf16*  qk    = (bf16*)(ws + 134217728);
    bf16*  vt    = (bf16*)(ws + 167772160);
    bf16*  wT    = (bf16*)(ws + 184549376);     // wqT | wkT | W'T
    float* bcat  = (float*)(ws + 186122240);
    float* bpv   = (float*)(ws + 186128384);
    float* stats = (float*)(ws + 186130432);
    float* parts = (float*)(ws + 186131456);
    float* spart = (float*)(ws + 186196992);    // 16384 x 16 f32
    float* rinv  = (float*)(ws + 187245568);    // 16384 f32

    gn_partial<<<dim3(64, NB), 256, 0, stream>>>((const float4*)x, parts);
    gn_reduce<<<1, 128, 0, stream>>>(parts, stats);
    gn_apply<<<8192, 256, 0, stream>>>((const float4*)x, stats, gsc, gbi, hf);
    wcast_t<<<dim3(64, 2), 256, 0, stream>>>(wq, wk, bq, bk, wT, bcat);
    prep_w<<<64, 256, 0, stream>>>(wv, wo, bv, bo, wT + 2 * CCH * CCH, bpv);

    // QK proj: [16384,512] @ [1024,512]^T (q scaled). 64x8 = 512 blocks.
    gemm256<128, 0><<<dim3(512, 1), 512, 0, stream>>>(
        hf, 512, 0, wT, 512, 0, qk, 1024, 0, bcat, nullptr, nullptr, nullptr,
        16384, 1024, 512, sscale);
    // V'^T direct: vt[d][tok] = W'^T @ hf^T. M=512, N=16384. 2x128 = 256 blk.
    gemm256<128, 3><<<dim3(256, 1), 512, 0, stream>>>(
        wT + 2 * CCH * CCH, 512, 0, hf, 512, 0, vt, 16384, 0,
        nullptr, nullptr, nullptr, nullptr, 512, 16384, 512, 0.f);
    // scores: exp(q @ k^T) bf16 + row-sum partials. 256 blocks x 4 batches.
    gemm256<256, 1><<<dim3(256, NB), 512, 0, stream>>>(
        qk, 1024, (size_t)NTOK * 1024, qk + 512, 1024, (size_t)NTOK * 1024,
        S_all, NTOK, (size_t)NTOK * NTOK, nullptr, nullptr, spart, nullptr,
        NTOK, NTOK, CCH, 0.f);
    rowsum_inv<<<64, 256, 0, stream>>>(spart, rinv);
    // out = x + (P_unnorm @ V') * rinv + bpv (final, f32). 64 x 4 batches.
    gemm256<128, 2><<<dim3(64, NB), 512, 0, stream>>>(
        S_all, NTOK, (size_t)NTOK * NTOK, vt, 16384, (size_t)NTOK,
        out, CCH, (size_t)NTOK * CCH, bpv, x, nullptr, rinv,
        NTOK, CCH, NTOK, 0.f);
  } else {
    // fallback (per-batch S): S1[33.6M] | qk[33.6M] | vt[16.8M] | wT | extras
    bf16*  S1    = (bf16*)(ws + 0);
    bf16*  hf    = (bf16*)(ws + 0);
    bf16*  qk    = (bf16*)(ws + 33554432);
    bf16*  vt    = (bf16*)(ws + 67108864);
    bf16*  wT    = (bf16*)(ws + 83886080);
    float* bcat  = (float*)(ws + 85458944);
    float* bpv   = (float*)(ws + 85463040);
    float* stats = (float*)(ws + 85465088);
    float* parts = (float*)(ws + 85466112);
    float* spart = (float*)(ws + 85531648);    // 4096 x 16 f32
    float* rinv  = (float*)(ws + 85793792);    // 4096 f32

    gn_partial<<<dim3(64, NB), 256, 0, stream>>>((const float4*)x, parts);
    gn_reduce<<<1, 128, 0, stream>>>(parts, stats);
    gn_apply<<<8192, 256, 0, stream>>>((const float4*)x, stats, gsc, gbi, hf);
    wcast_t<<<dim3(64, 2), 256, 0, stream>>>(wq, wk, bq, bk, wT, bcat);
    prep_w<<<64, 256, 0, stream>>>(wv, wo, bv, bo, wT + 2 * CCH * CCH, bpv);
    gemm256<128, 0><<<dim3(512, 1), 512, 0, stream>>>(
        hf, 512, 0, wT, 512, 0, qk, 1024, 0, bcat, nullptr, nullptr, nullptr,
        16384, 1024, 512, sscale);
    gemm256<128, 3><<<dim3(256, 1), 512, 0, stream>>>(
        wT + 2 * CCH * CCH, 512, 0, hf, 512, 0, vt, 16384, 0,
        nullptr, nullptr, nullptr, nullptr, 512, 16384, 512, 0.f);
    for (int b = 0; b < NB; ++b) {
      const bf16* qb = qk + (size_t)b * NTOK * 1024;
      gemm256<256, 1><<<dim3(256, 1), 512, 0, stream>>>(
          qb, 1024, 0, qb + 512, 1024, 0, S1, NTOK, 0, nullptr, nullptr,
          spart, nullptr, NTOK, NTOK, CCH, 0.f);
      rowsum_inv<<<16, 256, 0, stream>>>(spart, rinv);
      gemm256<128, 2><<<dim3(64, 1), 512, 0, stream>>>(
          S1, NTOK, 0, vt + (size_t)b * NTOK, 16384, 0,
          out + (size_t)b * NTOK * CCH, CCH, 0, bpv, x + (size_t)b * NTOK * CCH,
          nullptr, rinv, NTOK, CCH, NTOK, 0.f);
    }
  }
}

// Round 8
// 320.414 us; speedup vs baseline: 1.0925x; 1.0925x over previous
//
#include <hip/hip_runtime.h>
#include <hip/hip_bf16.h>
#include <math.h>

// ---------------------------------------------------------------------------
// FlaxLTX2AudioAttnBlock: GN -> QKV proj -> softmax(QK^T/sqrt(C)) V -> proj -> +x
// B=4, N=4096 tokens/batch, C=512, G=32 groups.
// R8: = R6 + MFMA cluster reordered k-slice-major (dependency distance 2->16;
//     back-to-back dependent MFMA pairs were stalling the matrix pipe ~2x).
//     R7's LDS-staged epilogue reverted (regressed: bank conflicts + wave
//     serialization).
// ---------------------------------------------------------------------------

typedef __bf16 bf16;
typedef float f32x4 __attribute__((ext_vector_type(4)));
typedef __bf16 bf16x8 __attribute__((ext_vector_type(8)));
typedef __bf16 bf16x4 __attribute__((ext_vector_type(4)));

#define AS1 __attribute__((address_space(1)))
#define AS3 __attribute__((address_space(3)))

#define NB   4
#define NTOK 4096
#define CCH  512
#define NGRP 32

__device__ __forceinline__ void gload_lds16(const void* g, void* l) {
  __builtin_amdgcn_global_load_lds((AS1 void*)(g), (AS3 void*)(l), 16, 0, 0);
}

// ---------------- GroupNorm stage 1: partial sums ---------------------------
__global__ __launch_bounds__(256) void gn_partial(const float4* __restrict__ x4,
                                                  float* __restrict__ partials) {
  const int chunk = blockIdx.x, b = blockIdx.y;
  const int tid = threadIdx.x;
  const size_t base = ((size_t)b * NTOK + (size_t)chunk * 64) * 128;  // float4s
  float s = 0.f, ss = 0.f;
  #pragma unroll 4
  for (int it = 0; it < 32; ++it) {
    const float4 v = x4[base + it * 256 + tid];
    s  += v.x + v.y + v.z + v.w;
    ss += v.x * v.x + v.y * v.y + v.z * v.z + v.w * v.w;
  }
  __shared__ float ls[256], lss[256];
  ls[tid] = s; lss[tid] = ss;
  __syncthreads();
  if (tid < 32) {
    float ps = 0.f, pss = 0.f;
    #pragma unroll
    for (int j = 0; j < 4; ++j) {
      ps  += ls[tid * 4 + j] + ls[128 + tid * 4 + j];
      pss += lss[tid * 4 + j] + lss[128 + tid * 4 + j];
    }
    const size_t o = (((size_t)b * 64 + chunk) * 32 + tid) * 2;
    partials[o] = ps; partials[o + 1] = pss;
  }
}

// ---------------- GroupNorm stage 2: reduce 64 chunks -> stats --------------
__global__ __launch_bounds__(128) void gn_reduce(const float* __restrict__ partials,
                                                 float* __restrict__ stats) {
  const int tid = threadIdx.x;          // tid = b*32 + g
  const int b = tid >> 5, g = tid & 31;
  float s = 0.f, ss = 0.f;
  for (int c = 0; c < 64; ++c) {
    const size_t o = (((size_t)b * 64 + c) * 32 + g) * 2;
    s += partials[o]; ss += partials[o + 1];
  }
  const float inv = 1.f / (NTOK * 16.f);
  const float mean = s * inv;
  const float var = ss * inv - mean * mean;
  stats[tid * 2] = mean;
  stats[tid * 2 + 1] = rsqrtf(var + 1e-6f);
}

// ---------------- normalize + affine + cast to bf16 -------------------------
__global__ __launch_bounds__(256) void gn_apply(const float4* __restrict__ x4,
                                                const float* __restrict__ stats,
                                                const float* __restrict__ gsc,
                                                const float* __restrict__ gbi,
                                                bf16* __restrict__ hf) {
  const int i = blockIdx.x * 256 + threadIdx.x;   // over 2,097,152 float4s
  const float4 v = x4[i];
  const size_t e = (size_t)i * 4;
  const int c = (int)(e & (CCH - 1));
  const int b = (int)(e >> 21);
  const int g = c >> 4;
  const float mean = stats[(b * NGRP + g) * 2];
  const float rstd = stats[(b * NGRP + g) * 2 + 1];
  bf16x4 o;
  o[0] = (bf16)((v.x - mean) * rstd * gsc[c + 0] + gbi[c + 0]);
  o[1] = (bf16)((v.y - mean) * rstd * gsc[c + 1] + gbi[c + 1]);
  o[2] = (bf16)((v.z - mean) * rstd * gsc[c + 2] + gbi[c + 2]);
  o[3] = (bf16)((v.w - mean) * rstd * gsc[c + 3] + gbi[c + 3]);
  *reinterpret_cast<bf16x4*>(&hf[e]) = o;
}

// ---------------- weight transpose+cast (wq, wk) + bias concat --------------
__global__ __launch_bounds__(256) void wcast_t(const float* __restrict__ wq,
                                               const float* __restrict__ wk,
                                               const float* __restrict__ bq,
                                               const float* __restrict__ bk,
                                               bf16* __restrict__ dst,
                                               float* __restrict__ bcat) {
  const int w = blockIdx.y;                // 0 = wq, 1 = wk
  const float* src = (w == 0) ? wq : wk;
  bf16* out = dst + (size_t)w * CCH * CCH;
  const int t = blockIdx.x;                // 8x8 tiles of 64x64
  const int tr = t >> 3, tc = t & 7;
  if (t == 0) {
    const float* bsrc = (w == 0) ? bq : bk;
    for (int i = threadIdx.x; i < CCH; i += 256) bcat[w * CCH + i] = bsrc[i];
  }
  __shared__ float tile[64][65];
  for (int i = threadIdx.x; i < 4096; i += 256) {
    const int r = i >> 6, c = i & 63;
    tile[r][c] = src[(size_t)(tr * 64 + r) * CCH + tc * 64 + c];
  }
  __syncthreads();
  for (int i = threadIdx.x; i < 4096; i += 256) {
    const int r = i >> 6, c = i & 63;
    out[(size_t)(tc * 64 + r) * CCH + tr * 64 + c] = (bf16)tile[c][r];
  }
}

// ---------------- prep: W'^T = (wv@wo)^T bf16; block 0 also bpv -------------
__global__ __launch_bounds__(256) void prep_w(const float* __restrict__ wv,
                                              const float* __restrict__ wo,
                                              const float* __restrict__ bv,
                                              const float* __restrict__ bo,
                                              bf16* __restrict__ wpT,
                                              float* __restrict__ bpv) {
  const int ta = blockIdx.x >> 3, tb = blockIdx.x & 7;   // 8x8 blocks of 64x64
  __shared__ float woS[64][65];   // [kk][aa]
  __shared__ float wvS[64][65];   // [bb][kk]
  const int t = threadIdx.x;
  if (blockIdx.x == 0) {           // bpv = bv @ wo + bo
    for (int j = t; j < CCH; j += 256) {
      float a2 = bo[j];
      for (int k2 = 0; k2 < CCH; ++k2) a2 += bv[k2] * wo[(size_t)k2 * CCH + j];
      bpv[j] = a2;
    }
  }
  const int aa0 = (t & 15) * 4, bb0 = (t >> 4) * 4;
  float acc[4][4] = {};
  for (int kt = 0; kt < CCH; kt += 64) {
    for (int i = t; i < 4096; i += 256) {
      const int r = i >> 6, c = i & 63;
      woS[r][c] = wo[(size_t)(kt + r) * CCH + ta * 64 + c];
      wvS[r][c] = wv[(size_t)(tb * 64 + r) * CCH + kt + c];
    }
    __syncthreads();
    #pragma unroll 8
    for (int kk = 0; kk < 64; ++kk) {
      float wo4[4], wv4[4];
      #pragma unroll
      for (int i2 = 0; i2 < 4; ++i2) { wo4[i2] = woS[kk][aa0 + i2]; wv4[i2] = wvS[bb0 + i2][kk]; }
      #pragma unroll
      for (int a2 = 0; a2 < 4; ++a2)
        #pragma unroll
        for (int b2 = 0; b2 < 4; ++b2)
          acc[a2][b2] += wo4[a2] * wv4[b2];
    }
    __syncthreads();
  }
  #pragma unroll
  for (int a2 = 0; a2 < 4; ++a2)
    #pragma unroll
    for (int b2 = 0; b2 < 4; ++b2)
      wpT[(size_t)(ta * 64 + aa0 + a2) * CCH + tb * 64 + bb0 + b2] = (bf16)acc[a2][b2];
}

// ---------------- row-sum reduce: partials[rows][16] -> rinv = 1/sum --------
__global__ __launch_bounds__(256) void rowsum_inv(const float* __restrict__ partials,
                                                  float* __restrict__ rinv) {
  const int row = blockIdx.x * 256 + threadIdx.x;
  const float* p = partials + (size_t)row * 16;
  float s = 0.f;
  #pragma unroll
  for (int j = 0; j < 16; ++j) s += p[j];
  rinv[row] = 1.f / s;
}

// ---------------- 4-phase 256xBN MFMA GEMM: C = A @ Bt^T (+ epilogue) -------
// 512 threads = 8 waves (2M x 4N). BM=256, BNt in {256,128}, BK=64.
// Main loop: 4-phase merged (R5), counted vmcnt; MFMA cluster ordered
// k-slice-major so consecutive MFMAs hit DIFFERENT accumulators (dependency
// distance 4*NREP instead of 2 -> matrix pipe fully pipelined).
// EPI: 0 = (+bias)*scale on cols<CCH, bf16 out (QK proj)
//      1 = exp(min(val,40)) bf16 out + per-block row-sum partials (scores)
//      2 = *rinv[row] +bias +resid, f32 out (PV -> final output)
//      3 = plain bf16 out (V'^T)
template <int BNt, int EPI>
__global__ __launch_bounds__(512, 2) void gemm256(
    const bf16* __restrict__ A, int lda, size_t sA,
    const bf16* __restrict__ Bt, int ldb, size_t sB,
    void* __restrict__ C, int ldc, size_t sC,
    const float* __restrict__ bias, const float* __restrict__ resid,
    float* __restrict__ partials, const float* __restrict__ rinv,
    int M, int N, int K, float scale) {
  constexpr int BK = 64;
  constexpr int WN = BNt / 4;        // per-wave N extent (64 or 32)
  constexpr int NREP = WN / 16;      // N fragments per wave (4 or 2)
  constexpr int BH = BNt / 2;        // B half-tile rows (128 or 64)
  constexpr int BISS = BNt / 128;    // gload issues per B half (2 or 1)

  __shared__ bf16 Al[2][256 * BK];
  __shared__ bf16 Bl[2][BNt * BK];

  A += (size_t)blockIdx.y * sA;
  Bt += (size_t)blockIdx.y * sB;

  const int tid = threadIdx.x;
  const int lane = tid & 63;
  const int wave = tid >> 6;
  const int wm = wave >> 2, wn = wave & 3;
  const int fr = lane & 15, fq = lane >> 4;
  const int nbn = N / BNt;
  int bx = blockIdx.x;
  const int nwg = gridDim.x;
  bx = (bx & 7) * (nwg >> 3) + (bx >> 3);    // XCD swizzle (all grids %8==0)
  const int bm = bx / nbn, bn = bx % nbn;

  // staging: thread covers 16B chunk; T2: global chunk = lds chunk ^ (row&7)
  const int srow = tid >> 3;                              // 0..63
  const int scol = (((tid & 7) ^ (srow & 7)) * 8);
  const bf16* Ab = A + (size_t)(bm * 256 + srow) * lda + scol;
  const bf16* Bb = Bt + (size_t)(bn * BNt + srow) * ldb + scol;

  // swizzled ds_read chunk offsets (elems): chunk (ks*4+fq) ^ (fr&7)
  const int xk = fr & 7;
  const int c0 = ((0 + fq) ^ xk) * 8;
  const int c1 = ((4 + fq) ^ xk) * 8;
  const int aroff = (wm * 128 + fr) * BK;
  const int broff = (wn * WN + fr) * BK;

  f32x4 acc[8][NREP];
  #pragma unroll
  for (int m2 = 0; m2 < 8; ++m2)
    #pragma unroll
    for (int n2 = 0; n2 < NREP; ++n2)
      acc[m2][n2] = f32x4{0.f, 0.f, 0.f, 0.f};
  bf16x8 af[4][2];
  bf16x8 bfr[NREP][2];

#define STAGE_A(buf, h, kt)                                                     \
  { gload_lds16(Ab + (size_t)((h) * 128) * lda + (kt),                          \
                &Al[buf][(h) * 8192 + wave * 512]);                             \
    gload_lds16(Ab + (size_t)((h) * 128 + 64) * lda + (kt),                     \
                &Al[buf][(h) * 8192 + 4096 + wave * 512]); }
#define STAGE_B(buf, h, kt)                                                     \
  { gload_lds16(Bb + (size_t)((h) * BH) * ldb + (kt),                           \
                &Bl[buf][(h) * BH * BK + wave * 512]);                          \
    if (BISS == 2)                                                              \
      gload_lds16(Bb + (size_t)((h) * BH + 64) * ldb + (kt),                    \
                  &Bl[buf][(h) * BH * BK + 4096 + wave * 512]); }
#define LOADA(buf, mh)                                                          \
  { _Pragma("unroll") for (int mi = 0; mi < 4; ++mi) {                          \
      af[mi][0] = *(const bf16x8*)&Al[buf][aroff + ((mh) * 64 + mi * 16) * BK + c0]; \
      af[mi][1] = *(const bf16x8*)&Al[buf][aroff + ((mh) * 64 + mi * 16) * BK + c1]; } }
#define LOADB(buf)                                                              \
  { _Pragma("unroll") for (int ni = 0; ni < NREP; ++ni) {                       \
      bfr[ni][0] = *(const bf16x8*)&Bl[buf][broff + (ni * 16) * BK + c0];       \
      bfr[ni][1] = *(const bf16x8*)&Bl[buf][broff + (ni * 16) * BK + c1]; } }
// k-slice-major: all acc frags at ks=0, then all at ks=1 (dep distance 4*NREP)
#define MMA(mh)                                                                 \
  { __builtin_amdgcn_s_setprio(1);                                              \
    _Pragma("unroll") for (int ks = 0; ks < 2; ++ks)                            \
      _Pragma("unroll") for (int mi = 0; mi < 4; ++mi)                          \
        _Pragma("unroll") for (int ni = 0; ni < NREP; ++ni)                     \
          acc[(mh) * 4 + mi][ni] = __builtin_amdgcn_mfma_f32_16x16x32_bf16(     \
              af[mi][ks], bfr[ni][ks], acc[(mh) * 4 + mi][ni], 0, 0, 0);        \
    __builtin_amdgcn_s_setprio(0); }
#define BARX() __builtin_amdgcn_s_barrier()
#define PIN() __builtin_amdgcn_sched_barrier(0)
#define LGKM0() { asm volatile("s_waitcnt lgkmcnt(0)" ::: "memory"); PIN(); }
#define VMW(n) asm volatile("s_waitcnt vmcnt(" #n ")" ::: "memory")
#define VMWSS() { if (BISS == 2) VMW(4); else VMW(3); }   // steady-state count

  // prologue: tile0 (4 halves) + A0,B0 of tile1 -> keep 2 halves in flight
  STAGE_A(0, 0, 0); STAGE_A(0, 1, 0);
  STAGE_B(0, 0, 0); STAGE_B(0, 1, 0);
  STAGE_A(1, 0, BK); STAGE_B(1, 0, BK);
  VMWSS();
  BARX();

  const int niter = K >> 7;      // 2 K-tiles (BK=64) per iteration
  for (int j = 0; j < niter; ++j) {
    const int kt1 = j * 128 + 64;
    const int kt2 = kt1 + 64, kt3 = kt1 + 128;
    const bool last = (j == niter - 1);
    // P1: tile t (buf0) mh=0 + B-all; stage A1(t+1),B1(t+1)->buf1
    LOADA(0, 0); LOADB(0); STAGE_A(1, 1, kt1); STAGE_B(1, 1, kt1);
    PIN(); BARX(); LGKM0(); MMA(0); BARX();
    // P2: mh=1 (B resident); stage A0(t+2),B0(t+2)->buf0; counted vmcnt
    LOADA(0, 1); if (!last) { STAGE_A(0, 0, kt2); STAGE_B(0, 0, kt2); }
    PIN(); BARX(); LGKM0(); MMA(1);
    if (last) { VMW(0); } else VMWSS();
    BARX();
    // P3: tile t+1 (buf1) mh=0 + B-all; stage A1(t+2),B1(t+2)->buf0
    LOADA(1, 0); LOADB(1); if (!last) { STAGE_A(0, 1, kt2); STAGE_B(0, 1, kt2); }
    PIN(); BARX(); LGKM0(); MMA(0); BARX();
    // P4: mh=1; stage A0(t+3),B0(t+3)->buf1; counted vmcnt
    LOADA(1, 1); if (!last) { STAGE_A(1, 0, kt3); STAGE_B(1, 0, kt3); }
    PIN(); BARX(); LGKM0(); MMA(1);
    if (!last) VMWSS();
    BARX();
  }

  // epilogue (R6 style: direct stores; scores add exp + shfl row-sums)
  const int crow0 = bm * 256 + wm * 128 + fq * 4;
  const int ccol0 = bn * BNt + wn * WN + fr;
  if constexpr (EPI == 1) {
    float* sums = (float*)&Al[0][0];            // 256 rows x 4 wn, reuse LDS
    #pragma unroll
    for (int mh = 0; mh < 2; ++mh)
      #pragma unroll
      for (int mi = 0; mi < 4; ++mi)
        #pragma unroll
        for (int jj = 0; jj < 4; ++jj) {
          const int row = crow0 + mh * 64 + mi * 16 + jj;
          float rs = 0.f;
          #pragma unroll
          for (int nr = 0; nr < NREP; ++nr) {
            const float e = __expf(fminf(acc[mh * 4 + mi][nr][jj], 40.f));
            rs += e;
            ((bf16*)C)[(size_t)blockIdx.y * sC + (size_t)row * ldc + ccol0 + nr * 16] = (bf16)e;
          }
          rs += __shfl_xor(rs, 1); rs += __shfl_xor(rs, 2);
          rs += __shfl_xor(rs, 4); rs += __shfl_xor(rs, 8);
          if (fr == 0)
            sums[(wm * 128 + mh * 64 + mi * 16 + fq * 4 + jj) * 4 + wn] = rs;
        }
    __syncthreads();
    if (tid < 256) {
      const float s4 = sums[tid * 4] + sums[tid * 4 + 1] +
                       sums[tid * 4 + 2] + sums[tid * 4 + 3];
      partials[((size_t)blockIdx.y * M + bm * 256 + tid) * (size_t)nbn + bn] = s4;
    }
  } else {
    #pragma unroll
    for (int mh = 0; mh < 2; ++mh)
      #pragma unroll
      for (int mi = 0; mi < 4; ++mi)
        #pragma unroll
        for (int nr = 0; nr < NREP; ++nr)
          #pragma unroll
          for (int jj = 0; jj < 4; ++jj) {
            const int row = crow0 + mh * 64 + mi * 16 + jj;
            const int col = ccol0 + nr * 16;
            const float val = acc[mh * 4 + mi][nr][jj];
            const size_t idx = (size_t)row * ldc + col;
            if constexpr (EPI == 0) {
              float vv = val + bias[col];
              if (col < CCH) vv *= scale;
              ((bf16*)C)[(size_t)blockIdx.y * sC + idx] = (bf16)vv;
            } else if constexpr (EPI == 3) {
              ((bf16*)C)[(size_t)blockIdx.y * sC + idx] = (bf16)val;
            } else {  // EPI == 2: PV final output
              float* Cf = (float*)C + (size_t)blockIdx.y * sC;
              const float ri = rinv[(size_t)blockIdx.y * M + row];
              Cf[idx] = val * ri + bias[col] + resid[(size_t)blockIdx.y * sC + idx];
            }
          }
  }
#undef STAGE_A
#undef STAGE_B
#undef LOADA
#undef LOADB
#undef MMA
#undef BARX
#undef PIN
#undef LGKM0
#undef VMW
#undef VMWSS
}

// ---------------------------------------------------------------------------
extern "C" void kernel_launch(void* const* d_in, const int* in_sizes, int n_in,
                              void* d_out, int out_size, void* d_ws, size_t ws_size,
                              hipStream_t stream) {
  const float* x   = (const float*)d_in[0];
  const float* gsc = (const float*)d_in[1];
  const float* gbi = (const float*)d_in[2];
  const float* wq  = (const float*)d_in[3];
  const float* bq  = (const float*)d_in[4];
  const float* wk  = (const float*)d_in[5];
  const float* bk  = (const float*)d_in[6];
  const float* wv  = (const float*)d_in[7];
  const float* bv  = (const float*)d_in[8];
  const float* wo  = (const float*)d_in[9];
  const float* bo  = (const float*)d_in[10];
  float* out = (float*)d_out;
  char* ws = (char*)d_ws;

  const float sscale = 0.044194173824159216f;  // 1/sqrt(512)
  const bool batched = ws_size >= 187311104ULL;

  if (batched) {
    // S_all[134.2M] | qk[33.6M] | vt[16.8M] | wT | bcat/bpv/stats | parts |
    // spart[1M] | rinv
    bf16*  S_all = (bf16*)(ws + 0);
    bf16*  hf    = (bf16*)(ws + 0);             // alias: dead before S written
    bf16*  qk    = (bf16*)(ws + 134217728);
    bf16*  vt    = (bf16*)(ws + 167772160);
    bf16*  wT    = (bf16*)(ws + 184549376);     // wqT | wkT | W'T
    float* bcat  = (float*)(ws + 186122240);
    float* bpv   = (float*)(ws + 186128384);
    float* stats = (float*)(ws + 186130432);
    float* parts = (float*)(ws + 186131456);
    float* spart = (float*)(ws + 186196992);    // 16384 x 16 f32
    float* rinv  = (float*)(ws + 187245568);    // 16384 f32

    gn_partial<<<dim3(64, NB), 256, 0, stream>>>((const float4*)x, parts);
    gn_reduce<<<1, 128, 0, stream>>>(parts, stats);
    gn_apply<<<8192, 256, 0, stream>>>((const float4*)x, stats, gsc, gbi, hf);
    wcast_t<<<dim3(64, 2), 256, 0, stream>>>(wq, wk, bq, bk, wT, bcat);
    prep_w<<<64, 256, 0, stream>>>(wv, wo, bv, bo, wT + 2 * CCH * CCH, bpv);

    // QK proj: [16384,512] @ [1024,512]^T (q scaled). 64x8 = 512 blocks.
    gemm256<128, 0><<<dim3(512, 1), 512, 0, stream>>>(
        hf, 512, 0, wT, 512, 0, qk, 1024, 0, bcat, nullptr, nullptr, nullptr,
        16384, 1024, 512, sscale);
    // V'^T direct: vt[d][tok] = W'^T @ hf^T. M=512, N=16384. 2x128 = 256 blk.
    gemm256<128, 3><<<dim3(256, 1), 512, 0, stream>>>(
        wT + 2 * CCH * CCH, 512, 0, hf, 512, 0, vt, 16384, 0,
        nullptr, nullptr, nullptr, nullptr, 512, 16384, 512, 0.f);
    // scores: exp(q @ k^T) bf16 + row-sum partials. 256 blocks x 4 batches.
    gemm256<256, 1><<<dim3(256, NB), 512, 0, stream>>>(
        qk, 1024, (size_t)NTOK * 1024, qk + 512, 1024, (size_t)NTOK * 1024,
        S_all, NTOK, (size_t)NTOK * NTOK, nullptr, nullptr, spart, nullptr,
        NTOK, NTOK, CCH, 0.f);
    rowsum_inv<<<64, 256, 0, stream>>>(spart, rinv);
    // out = x + (P_unnorm @ V') * rinv + bpv (final, f32). 64 x 4 batches.
    gemm256<128, 2><<<dim3(64, NB), 512, 0, stream>>>(
        S_all, NTOK, (size_t)NTOK * NTOK, vt, 16384, (size_t)NTOK,
        out, CCH, (size_t)NTOK * CCH, bpv, x, nullptr, rinv,
        NTOK, CCH, NTOK, 0.f);
  } else {
    // fallback (per-batch S): S1[33.6M] | qk[33.6M] | vt[16.8M] | wT | extras
    bf16*  S1    = (bf16*)(ws + 0);
    bf16*  hf    = (bf16*)(ws + 0);
    bf16*  qk    = (bf16*)(ws + 33554432);
    bf16*  vt    = (bf16*)(ws + 67108864);
    bf16*  wT    = (bf16*)(ws + 83886080);
    float* bcat  = (float*)(ws + 85458944);
    float* bpv   = (float*)(ws + 85463040);
    float* stats = (float*)(ws + 85465088);
    float* parts = (float*)(ws + 85466112);
    float* spart = (float*)(ws + 85531648);    // 4096 x 16 f32
    float* rinv  = (float*)(ws + 85793792);    // 4096 f32

    gn_partial<<<dim3(64, NB), 256, 0, stream>>>((const float4*)x, parts);
    gn_reduce<<<1, 128, 0, stream>>>(parts, stats);
    gn_apply<<<8192, 256, 0, stream>>>((const float4*)x, stats, gsc, gbi, hf);
    wcast_t<<<dim3(64, 2), 256, 0, stream>>>(wq, wk, bq, bk, wT, bcat);
    prep_w<<<64, 256, 0, stream>>>(wv, wo, bv, bo, wT + 2 * CCH * CCH, bpv);
    gemm256<128, 0><<<dim3(512, 1), 512, 0, stream>>>(
        hf, 512, 0, wT, 512, 0, qk, 1024, 0, bcat, nullptr, nullptr, nullptr,
        16384, 1024, 512, sscale);
    gemm256<128, 3><<<dim3(256, 1), 512, 0, stream>>>(
        wT + 2 * CCH * CCH, 512, 0, hf, 512, 0, vt, 16384, 0,
        nullptr, nullptr, nullptr, nullptr, 512, 16384, 512, 0.f);
    for (int b = 0; b < NB; ++b) {
      const bf16* qb = qk + (size_t)b * NTOK * 1024;
      gemm256<256, 1><<<dim3(256, 1), 512, 0, stream>>>(
          qb, 1024, 0, qb + 512, 1024, 0, S1, NTOK, 0, nullptr, nullptr,
          spart, nullptr, NTOK, NTOK, CCH, 0.f);
      rowsum_inv<<<16, 256, 0, stream>>>(spart, rinv);
      gemm256<128, 2><<<dim3(64, 1), 512, 0, stream>>>(
          S1, NTOK, 0, vt + (size_t)b * NTOK, 16384, 0,
          out + (size_t)b * NTOK * CCH, CCH, 0, bpv, x + (size_t)b * NTOK * CCH,
          nullptr, rinv, NTOK, CCH, NTOK, 0.f);
    }
  }
}

// Round 9
// 314.666 us; speedup vs baseline: 1.1125x; 1.0183x over previous
//
#include <hip/hip_runtime.h>
#include <hip/hip_bf16.h>
#include <math.h>

// ---------------------------------------------------------------------------
// FlaxLTX2AudioAttnBlock: GN -> QKV proj -> softmax(QK^T/sqrt(C)) V -> proj -> +x
// B=4, N=4096 tokens/batch, C=512, G=32 groups.
// R9: XCD panel-coherent block mapping for QK/scores/PV (all bn-mates of one
//     bm-panel -> same XCD so the shared A-panel stays in that XCD's L2;
//     old swizzle scattered panel-mates across XCDs -> every read via L3).
//     Main loop / epilogues unchanged from R8.
// ---------------------------------------------------------------------------

typedef __bf16 bf16;
typedef float f32x4 __attribute__((ext_vector_type(4)));
typedef __bf16 bf16x8 __attribute__((ext_vector_type(8)));
typedef __bf16 bf16x4 __attribute__((ext_vector_type(4)));

#define AS1 __attribute__((address_space(1)))
#define AS3 __attribute__((address_space(3)))

#define NB   4
#define NTOK 4096
#define CCH  512
#define NGRP 32

__device__ __forceinline__ void gload_lds16(const void* g, void* l) {
  __builtin_amdgcn_global_load_lds((AS1 void*)(g), (AS3 void*)(l), 16, 0, 0);
}

// ---------------- GroupNorm stage 1: partial sums ---------------------------
__global__ __launch_bounds__(256) void gn_partial(const float4* __restrict__ x4,
                                                  float* __restrict__ partials) {
  const int chunk = blockIdx.x, b = blockIdx.y;
  const int tid = threadIdx.x;
  const size_t base = ((size_t)b * NTOK + (size_t)chunk * 64) * 128;  // float4s
  float s = 0.f, ss = 0.f;
  #pragma unroll 4
  for (int it = 0; it < 32; ++it) {
    const float4 v = x4[base + it * 256 + tid];
    s  += v.x + v.y + v.z + v.w;
    ss += v.x * v.x + v.y * v.y + v.z * v.z + v.w * v.w;
  }
  __shared__ float ls[256], lss[256];
  ls[tid] = s; lss[tid] = ss;
  __syncthreads();
  if (tid < 32) {
    float ps = 0.f, pss = 0.f;
    #pragma unroll
    for (int j = 0; j < 4; ++j) {
      ps  += ls[tid * 4 + j] + ls[128 + tid * 4 + j];
      pss += lss[tid * 4 + j] + lss[128 + tid * 4 + j];
    }
    const size_t o = (((size_t)b * 64 + chunk) * 32 + tid) * 2;
    partials[o] = ps; partials[o + 1] = pss;
  }
}

// ---------------- GroupNorm stage 2: reduce 64 chunks -> stats --------------
__global__ __launch_bounds__(128) void gn_reduce(const float* __restrict__ partials,
                                                 float* __restrict__ stats) {
  const int tid = threadIdx.x;          // tid = b*32 + g
  const int b = tid >> 5, g = tid & 31;
  float s = 0.f, ss = 0.f;
  for (int c = 0; c < 64; ++c) {
    const size_t o = (((size_t)b * 64 + c) * 32 + g) * 2;
    s += partials[o]; ss += partials[o + 1];
  }
  const float inv = 1.f / (NTOK * 16.f);
  const float mean = s * inv;
  const float var = ss * inv - mean * mean;
  stats[tid * 2] = mean;
  stats[tid * 2 + 1] = rsqrtf(var + 1e-6f);
}

// ---------------- normalize + affine + cast to bf16 -------------------------
__global__ __launch_bounds__(256) void gn_apply(const float4* __restrict__ x4,
                                                const float* __restrict__ stats,
                                                const float* __restrict__ gsc,
                                                const float* __restrict__ gbi,
                                                bf16* __restrict__ hf) {
  const int i = blockIdx.x * 256 + threadIdx.x;   // over 2,097,152 float4s
  const float4 v = x4[i];
  const size_t e = (size_t)i * 4;
  const int c = (int)(e & (CCH - 1));
  const int b = (int)(e >> 21);
  const int g = c >> 4;
  const float mean = stats[(b * NGRP + g) * 2];
  const float rstd = stats[(b * NGRP + g) * 2 + 1];
  bf16x4 o;
  o[0] = (bf16)((v.x - mean) * rstd * gsc[c + 0] + gbi[c + 0]);
  o[1] = (bf16)((v.y - mean) * rstd * gsc[c + 1] + gbi[c + 1]);
  o[2] = (bf16)((v.z - mean) * rstd * gsc[c + 2] + gbi[c + 2]);
  o[3] = (bf16)((v.w - mean) * rstd * gsc[c + 3] + gbi[c + 3]);
  *reinterpret_cast<bf16x4*>(&hf[e]) = o;
}

// ---------------- weight transpose+cast (wq, wk) + bias concat --------------
__global__ __launch_bounds__(256) void wcast_t(const float* __restrict__ wq,
                                               const float* __restrict__ wk,
                                               const float* __restrict__ bq,
                                               const float* __restrict__ bk,
                                               bf16* __restrict__ dst,
                                               float* __restrict__ bcat) {
  const int w = blockIdx.y;                // 0 = wq, 1 = wk
  const float* src = (w == 0) ? wq : wk;
  bf16* out = dst + (size_t)w * CCH * CCH;
  const int t = blockIdx.x;                // 8x8 tiles of 64x64
  const int tr = t >> 3, tc = t & 7;
  if (t == 0) {
    const float* bsrc = (w == 0) ? bq : bk;
    for (int i = threadIdx.x; i < CCH; i += 256) bcat[w * CCH + i] = bsrc[i];
  }
  __shared__ float tile[64][65];
  for (int i = threadIdx.x; i < 4096; i += 256) {
    const int r = i >> 6, c = i & 63;
    tile[r][c] = src[(size_t)(tr * 64 + r) * CCH + tc * 64 + c];
  }
  __syncthreads();
  for (int i = threadIdx.x; i < 4096; i += 256) {
    const int r = i >> 6, c = i & 63;
    out[(size_t)(tc * 64 + r) * CCH + tr * 64 + c] = (bf16)tile[c][r];
  }
}

// ---------------- prep: W'^T = (wv@wo)^T bf16; block 0 also bpv -------------
__global__ __launch_bounds__(256) void prep_w(const float* __restrict__ wv,
                                              const float* __restrict__ wo,
                                              const float* __restrict__ bv,
                                              const float* __restrict__ bo,
                                              bf16* __restrict__ wpT,
                                              float* __restrict__ bpv) {
  const int ta = blockIdx.x >> 3, tb = blockIdx.x & 7;   // 8x8 blocks of 64x64
  __shared__ float woS[64][65];   // [kk][aa]
  __shared__ float wvS[64][65];   // [bb][kk]
  const int t = threadIdx.x;
  if (blockIdx.x == 0) {           // bpv = bv @ wo + bo
    for (int j = t; j < CCH; j += 256) {
      float a2 = bo[j];
      for (int k2 = 0; k2 < CCH; ++k2) a2 += bv[k2] * wo[(size_t)k2 * CCH + j];
      bpv[j] = a2;
    }
  }
  const int aa0 = (t & 15) * 4, bb0 = (t >> 4) * 4;
  float acc[4][4] = {};
  for (int kt = 0; kt < CCH; kt += 64) {
    for (int i = t; i < 4096; i += 256) {
      const int r = i >> 6, c = i & 63;
      woS[r][c] = wo[(size_t)(kt + r) * CCH + ta * 64 + c];
      wvS[r][c] = wv[(size_t)(tb * 64 + r) * CCH + kt + c];
    }
    __syncthreads();
    #pragma unroll 8
    for (int kk = 0; kk < 64; ++kk) {
      float wo4[4], wv4[4];
      #pragma unroll
      for (int i2 = 0; i2 < 4; ++i2) { wo4[i2] = woS[kk][aa0 + i2]; wv4[i2] = wvS[bb0 + i2][kk]; }
      #pragma unroll
      for (int a2 = 0; a2 < 4; ++a2)
        #pragma unroll
        for (int b2 = 0; b2 < 4; ++b2)
          acc[a2][b2] += wo4[a2] * wv4[b2];
    }
    __syncthreads();
  }
  #pragma unroll
  for (int a2 = 0; a2 < 4; ++a2)
    #pragma unroll
    for (int b2 = 0; b2 < 4; ++b2)
      wpT[(size_t)(ta * 64 + aa0 + a2) * CCH + tb * 64 + bb0 + b2] = (bf16)acc[a2][b2];
}

// ---------------- row-sum reduce: partials[rows][16] -> rinv = 1/sum --------
__global__ __launch_bounds__(256) void rowsum_inv(const float* __restrict__ partials,
                                                  float* __restrict__ rinv) {
  const int row = blockIdx.x * 256 + threadIdx.x;
  const float* p = partials + (size_t)row * 16;
  float s = 0.f;
  #pragma unroll
  for (int j = 0; j < 16; ++j) s += p[j];
  rinv[row] = 1.f / s;
}

// ---------------- 4-phase 256xBN MFMA GEMM: C = A @ Bt^T (+ epilogue) -------
// 512 threads = 8 waves (2M x 4N). BM=256, BNt in {256,128}, BK=64.
// Main loop: 4-phase merged, counted vmcnt, k-slice-major MFMA order.
// Block mapping (EPI != 3): XCD panel-coherent -- all bn-mates of a bm-panel
// get the same (dispatch & 7) => same XCD => shared A-panel is L2-resident
// (PV: 2MB S-panel x4 mates; scores: 256KB x16 mates). Requires nbm % 8 == 0.
// EPI==3 (VT, nbm=2): old bijective XCD swizzle.
// EPI: 0 = (+bias)*scale on cols<CCH, bf16 out (QK proj)
//      1 = exp(min(val,40)) bf16 out + per-block row-sum partials (scores)
//      2 = *rinv[row] +bias +resid, f32 out (PV -> final output)
//      3 = plain bf16 out (V'^T)
template <int BNt, int EPI>
__global__ __launch_bounds__(512, 2) void gemm256(
    const bf16* __restrict__ A, int lda, size_t sA,
    const bf16* __restrict__ Bt, int ldb, size_t sB,
    void* __restrict__ C, int ldc, size_t sC,
    const float* __restrict__ bias, const float* __restrict__ resid,
    float* __restrict__ partials, const float* __restrict__ rinv,
    int M, int N, int K, float scale) {
  constexpr int BK = 64;
  constexpr int WN = BNt / 4;        // per-wave N extent (64 or 32)
  constexpr int NREP = WN / 16;      // N fragments per wave (4 or 2)
  constexpr int BH = BNt / 2;        // B half-tile rows (128 or 64)
  constexpr int BISS = BNt / 128;    // gload issues per B half (2 or 1)

  __shared__ bf16 Al[2][256 * BK];
  __shared__ bf16 Bl[2][BNt * BK];

  A += (size_t)blockIdx.y * sA;
  Bt += (size_t)blockIdx.y * sB;

  const int tid = threadIdx.x;
  const int lane = tid & 63;
  const int wave = tid >> 6;
  const int wm = wave >> 2, wn = wave & 3;
  const int fr = lane & 15, fq = lane >> 4;
  const int nbn = N / BNt;
  int bm, bn;
  if constexpr (EPI == 3) {
    const int nwg = gridDim.x;
    const int bx = (blockIdx.x & 7) * (nwg >> 3) + (blockIdx.x >> 3);
    bm = bx / nbn; bn = bx % nbn;
  } else {
    // panel-coherent: same-bm blocks share (dispatch & 7) -> same XCD
    const int r = blockIdx.x & 7, q = blockIdx.x >> 3;
    const int pg = q / nbn;
    bm = r + 8 * pg;
    bn = q - pg * nbn;
  }

  // staging: thread covers 16B chunk; T2: global chunk = lds chunk ^ (row&7)
  const int srow = tid >> 3;                              // 0..63
  const int scol = (((tid & 7) ^ (srow & 7)) * 8);
  const bf16* Ab = A + (size_t)(bm * 256 + srow) * lda + scol;
  const bf16* Bb = Bt + (size_t)(bn * BNt + srow) * ldb + scol;

  // swizzled ds_read chunk offsets (elems): chunk (ks*4+fq) ^ (fr&7)
  const int xk = fr & 7;
  const int c0 = ((0 + fq) ^ xk) * 8;
  const int c1 = ((4 + fq) ^ xk) * 8;
  const int aroff = (wm * 128 + fr) * BK;
  const int broff = (wn * WN + fr) * BK;

  f32x4 acc[8][NREP];
  #pragma unroll
  for (int m2 = 0; m2 < 8; ++m2)
    #pragma unroll
    for (int n2 = 0; n2 < NREP; ++n2)
      acc[m2][n2] = f32x4{0.f, 0.f, 0.f, 0.f};
  bf16x8 af[4][2];
  bf16x8 bfr[NREP][2];

#define STAGE_A(buf, h, kt)                                                     \
  { gload_lds16(Ab + (size_t)((h) * 128) * lda + (kt),                          \
                &Al[buf][(h) * 8192 + wave * 512]);                             \
    gload_lds16(Ab + (size_t)((h) * 128 + 64) * lda + (kt),                     \
                &Al[buf][(h) * 8192 + 4096 + wave * 512]); }
#define STAGE_B(buf, h, kt)                                                     \
  { gload_lds16(Bb + (size_t)((h) * BH) * ldb + (kt),                           \
                &Bl[buf][(h) * BH * BK + wave * 512]);                          \
    if (BISS == 2)                                                              \
      gload_lds16(Bb + (size_t)((h) * BH + 64) * ldb + (kt),                    \
                  &Bl[buf][(h) * BH * BK + 4096 + wave * 512]); }
#define LOADA(buf, mh)                                                          \
  { _Pragma("unroll") for (int mi = 0; mi < 4; ++mi) {                          \
      af[mi][0] = *(const bf16x8*)&Al[buf][aroff + ((mh) * 64 + mi * 16) * BK + c0]; \
      af[mi][1] = *(const bf16x8*)&Al[buf][aroff + ((mh) * 64 + mi * 16) * BK + c1]; } }
#define LOADB(buf)                                                              \
  { _Pragma("unroll") for (int ni = 0; ni < NREP; ++ni) {                       \
      bfr[ni][0] = *(const bf16x8*)&Bl[buf][broff + (ni * 16) * BK + c0];       \
      bfr[ni][1] = *(const bf16x8*)&Bl[buf][broff + (ni * 16) * BK + c1]; } }
// k-slice-major: all acc frags at ks=0, then all at ks=1 (dep distance 4*NREP)
#define MMA(mh)                                                                 \
  { __builtin_amdgcn_s_setprio(1);                                              \
    _Pragma("unroll") for (int ks = 0; ks < 2; ++ks)                            \
      _Pragma("unroll") for (int mi = 0; mi < 4; ++mi)                          \
        _Pragma("unroll") for (int ni = 0; ni < NREP; ++ni)                     \
          acc[(mh) * 4 + mi][ni] = __builtin_amdgcn_mfma_f32_16x16x32_bf16(     \
              af[mi][ks], bfr[ni][ks], acc[(mh) * 4 + mi][ni], 0, 0, 0);        \
    __builtin_amdgcn_s_setprio(0); }
#define BARX() __builtin_amdgcn_s_barrier()
#define PIN() __builtin_amdgcn_sched_barrier(0)
#define LGKM0() { asm volatile("s_waitcnt lgkmcnt(0)" ::: "memory"); PIN(); }
#define VMW(n) asm volatile("s_waitcnt vmcnt(" #n ")" ::: "memory")
#define VMWSS() { if (BISS == 2) VMW(4); else VMW(3); }   // steady-state count

  // prologue: tile0 (4 halves) + A0,B0 of tile1 -> keep 2 halves in flight
  STAGE_A(0, 0, 0); STAGE_A(0, 1, 0);
  STAGE_B(0, 0, 0); STAGE_B(0, 1, 0);
  STAGE_A(1, 0, BK); STAGE_B(1, 0, BK);
  VMWSS();
  BARX();

  const int niter = K >> 7;      // 2 K-tiles (BK=64) per iteration
  for (int j = 0; j < niter; ++j) {
    const int kt1 = j * 128 + 64;
    const int kt2 = kt1 + 64, kt3 = kt1 + 128;
    const bool last = (j == niter - 1);
    // P1: tile t (buf0) mh=0 + B-all; stage A1(t+1),B1(t+1)->buf1
    LOADA(0, 0); LOADB(0); STAGE_A(1, 1, kt1); STAGE_B(1, 1, kt1);
    PIN(); BARX(); LGKM0(); MMA(0); BARX();
    // P2: mh=1 (B resident); stage A0(t+2),B0(t+2)->buf0; counted vmcnt
    LOADA(0, 1); if (!last) { STAGE_A(0, 0, kt2); STAGE_B(0, 0, kt2); }
    PIN(); BARX(); LGKM0(); MMA(1);
    if (last) { VMW(0); } else VMWSS();
    BARX();
    // P3: tile t+1 (buf1) mh=0 + B-all; stage A1(t+2),B1(t+2)->buf0
    LOADA(1, 0); LOADB(1); if (!last) { STAGE_A(0, 1, kt2); STAGE_B(0, 1, kt2); }
    PIN(); BARX(); LGKM0(); MMA(0); BARX();
    // P4: mh=1; stage A0(t+3),B0(t+3)->buf1; counted vmcnt
    LOADA(1, 1); if (!last) { STAGE_A(1, 0, kt3); STAGE_B(1, 0, kt3); }
    PIN(); BARX(); LGKM0(); MMA(1);
    if (!last) VMWSS();
    BARX();
  }

  // epilogue (R6 style: direct stores; scores add exp + shfl row-sums)
  const int crow0 = bm * 256 + wm * 128 + fq * 4;
  const int ccol0 = bn * BNt + wn * WN + fr;
  if constexpr (EPI == 1) {
    float* sums = (float*)&Al[0][0];            // 256 rows x 4 wn, reuse LDS
    #pragma unroll
    for (int mh = 0; mh < 2; ++mh)
      #pragma unroll
      for (int mi = 0; mi < 4; ++mi)
        #pragma unroll
        for (int jj = 0; jj < 4; ++jj) {
          const int row = crow0 + mh * 64 + mi * 16 + jj;
          float rs = 0.f;
          #pragma unroll
          for (int nr = 0; nr < NREP; ++nr) {
            const float e = __expf(fminf(acc[mh * 4 + mi][nr][jj], 40.f));
            rs += e;
            ((bf16*)C)[(size_t)blockIdx.y * sC + (size_t)row * ldc + ccol0 + nr * 16] = (bf16)e;
          }
          rs += __shfl_xor(rs, 1); rs += __shfl_xor(rs, 2);
          rs += __shfl_xor(rs, 4); rs += __shfl_xor(rs, 8);
          if (fr == 0)
            sums[(wm * 128 + mh * 64 + mi * 16 + fq * 4 + jj) * 4 + wn] = rs;
        }
    __syncthreads();
    if (tid < 256) {
      const float s4 = sums[tid * 4] + sums[tid * 4 + 1] +
                       sums[tid * 4 + 2] + sums[tid * 4 + 3];
      partials[((size_t)blockIdx.y * M + bm * 256 + tid) * (size_t)nbn + bn] = s4;
    }
  } else {
    #pragma unroll
    for (int mh = 0; mh < 2; ++mh)
      #pragma unroll
      for (int mi = 0; mi < 4; ++mi)
        #pragma unroll
        for (int nr = 0; nr < NREP; ++nr)
          #pragma unroll
          for (int jj = 0; jj < 4; ++jj) {
            const int row = crow0 + mh * 64 + mi * 16 + jj;
            const int col = ccol0 + nr * 16;
            const float val = acc[mh * 4 + mi][nr][jj];
            const size_t idx = (size_t)row * ldc + col;
            if constexpr (EPI == 0) {
              float vv = val + bias[col];
              if (col < CCH) vv *= scale;
              ((bf16*)C)[(size_t)blockIdx.y * sC + idx] = (bf16)vv;
            } else if constexpr (EPI == 3) {
              ((bf16*)C)[(size_t)blockIdx.y * sC + idx] = (bf16)val;
            } else {  // EPI == 2: PV final output
              float* Cf = (float*)C + (size_t)blockIdx.y * sC;
              const float ri = rinv[(size_t)blockIdx.y * M + row];
              Cf[idx] = val * ri + bias[col] + resid[(size_t)blockIdx.y * sC + idx];
            }
          }
  }
#undef STAGE_A
#undef STAGE_B
#undef LOADA
#undef LOADB
#undef MMA
#undef BARX
#undef PIN
#undef LGKM0
#undef VMW
#undef VMWSS
}

// ---------------------------------------------------------------------------
extern "C" void kernel_launch(void* const* d_in, const int* in_sizes, int n_in,
                              void* d_out, int out_size, void* d_ws, size_t ws_size,
                              hipStream_t stream) {
  const float* x   = (const float*)d_in[0];
  const float* gsc = (const float*)d_in[1];
  const float* gbi = (const float*)d_in[2];
  const float* wq  = (const float*)d_in[3];
  const float* bq  = (const float*)d_in[4];
  const float* wk  = (const float*)d_in[5];
  const float* bk  = (const float*)d_in[6];
  const float* wv  = (const float*)d_in[7];
  const float* bv  = (const float*)d_in[8];
  const float* wo  = (const float*)d_in[9];
  const float* bo  = (const float*)d_in[10];
  float* out = (float*)d_out;
  char* ws = (char*)d_ws;

  const float sscale = 0.044194173824159216f;  // 1/sqrt(512)
  const bool batched = ws_size >= 187311104ULL;

  if (batched) {
    // S_all[134.2M] | qk[33.6M] | vt[16.8M] | wT | bcat/bpv/stats | parts |
    // spart[1M] | rinv
    bf16*  S_all = (bf16*)(ws + 0);
    bf16*  hf    = (bf16*)(ws + 0);             // alias: dead before S written
    bf16*  qk    = (bf16*)(ws + 134217728);
    bf16*  vt    = (bf16*)(ws + 167772160);
    bf16*  wT    = (bf16*)(ws + 184549376);     // wqT | wkT | W'T
    float* bcat  = (float*)(ws + 186122240);
    float* bpv   = (float*)(ws + 186128384);
    float* stats = (float*)(ws + 186130432);
    float* parts = (float*)(ws + 186131456);
    float* spart = (float*)(ws + 186196992);    // 16384 x 16 f32
    float* rinv  = (float*)(ws + 187245568);    // 16384 f32

    gn_partial<<<dim3(64, NB), 256, 0, stream>>>((const float4*)x, parts);
    gn_reduce<<<1, 128, 0, stream>>>(parts, stats);
    gn_apply<<<8192, 256, 0, stream>>>((const float4*)x, stats, gsc, gbi, hf);
    wcast_t<<<dim3(64, 2), 256, 0, stream>>>(wq, wk, bq, bk, wT, bcat);
    prep_w<<<64, 256, 0, stream>>>(wv, wo, bv, bo, wT + 2 * CCH * CCH, bpv);

    // QK proj: [16384,512] @ [1024,512]^T (q scaled). 64x8 = 512 blocks.
    gemm256<128, 0><<<dim3(512, 1), 512, 0, stream>>>(
        hf, 512, 0, wT, 512, 0, qk, 1024, 0, bcat, nullptr, nullptr, nullptr,
        16384, 1024, 512, sscale);
    // V'^T direct: vt[d][tok] = W'^T @ hf^T. M=512, N=16384. 2x128 = 256 blk.
    gemm256<128, 3><<<dim3(256, 1), 512, 0, stream>>>(
        wT + 2 * CCH * CCH, 512, 0, hf, 512, 0, vt, 16384, 0,
        nullptr, nullptr, nullptr, nullptr, 512, 16384, 512, 0.f);
    // scores: exp(q @ k^T) bf16 + row-sum partials. 256 blocks x 4 batches.
    gemm256<256, 1><<<dim3(256, NB), 512, 0, stream>>>(
        qk, 1024, (size_t)NTOK * 1024, qk + 512, 1024, (size_t)NTOK * 1024,
        S_all, NTOK, (size_t)NTOK * NTOK, nullptr, nullptr, spart, nullptr,
        NTOK, NTOK, CCH, 0.f);
    rowsum_inv<<<64, 256, 0, stream>>>(spart, rinv);
    // out = x + (P_unnorm @ V') * rinv + bpv (final, f32). 64 x 4 batches.
    gemm256<128, 2><<<dim3(64, NB), 512, 0, stream>>>(
        S_all, NTOK, (size_t)NTOK * NTOK, vt, 16384, (size_t)NTOK,
        out, CCH, (size_t)NTOK * CCH, bpv, x, nullptr, rinv,
        NTOK, CCH, NTOK, 0.f);
  } else {
    // fallback (per-batch S): S1[33.6M] | qk[33.6M] | vt[16.8M] | wT | extras
    bf16*  S1    = (bf16*)(ws + 0);
    bf16*  hf    = (bf16*)(ws + 0);
    bf16*  qk    = (bf16*)(ws + 33554432);
    bf16*  vt    = (bf16*)(ws + 67108864);
    bf16*  wT    = (bf16*)(ws + 83886080);
    float* bcat  = (float*)(ws + 85458944);
    float* bpv   = (float*)(ws + 85463040);
    float* stats = (float*)(ws + 85465088);
    float* parts = (float*)(ws + 85466112);
    float* spart = (float*)(ws + 85531648);    // 4096 x 16 f32
    float* rinv  = (float*)(ws + 85793792);    // 4096 f32

    gn_partial<<<dim3(64, NB), 256, 0, stream>>>((const float4*)x, parts);
    gn_reduce<<<1, 128, 0, stream>>>(parts, stats);
    gn_apply<<<8192, 256, 0, stream>>>((const float4*)x, stats, gsc, gbi, hf);
    wcast_t<<<dim3(64, 2), 256, 0, stream>>>(wq, wk, bq, bk, wT, bcat);
    prep_w<<<64, 256, 0, stream>>>(wv, wo, bv, bo, wT + 2 * CCH * CCH, bpv);
    gemm256<128, 0><<<dim3(512, 1), 512, 0, stream>>>(
        hf, 512, 0, wT, 512, 0, qk, 1024, 0, bcat, nullptr, nullptr, nullptr,
        16384, 1024, 512, sscale);
    gemm256<128, 3><<<dim3(256, 1), 512, 0, stream>>>(
        wT + 2 * CCH * CCH, 512, 0, hf, 512, 0, vt, 16384, 0,
        nullptr, nullptr, nullptr, nullptr, 512, 16384, 512, 0.f);
    for (int b = 0; b < NB; ++b) {
      const bf16* qb = qk + (size_t)b * NTOK * 1024;
      gemm256<256, 1><<<dim3(256, 1), 512, 0, stream>>>(
          qb, 1024, 0, qb + 512, 1024, 0, S1, NTOK, 0, nullptr, nullptr,
          spart, nullptr, NTOK, NTOK, CCH, 0.f);
      rowsum_inv<<<16, 256, 0, stream>>>(spart, rinv);
      gemm256<128, 2><<<dim3(64, 1), 512, 0, stream>>>(
          S1, NTOK, 0, vt + (size_t)b * NTOK, 16384, 0,
          out + (size_t)b * NTOK * CCH, CCH, 0, bpv, x + (size_t)b * NTOK * CCH,
          nullptr, rinv, NTOK, CCH, NTOK, 0.f);
    }
  }
}